// Round 2
// baseline (113.359 us; speedup 1.0000x reference)
//
#include <hip/hip_runtime.h>

// x_lab [16,3,512,512] fp32, patch=3, alpha from d_in[2], out [16,2,512,512] fp32
#define NB   16
#define HH   512
#define WW   512
#define HWSZ (HH * WW)

// Load 6 consecutive floats (col-1 .. col+4) for one row of one channel:
// aligned float4 + neighbors via wave shuffle; wave-edge lanes do a masked
// scalar load; out-of-image rows / cols produce 0 (zero padding).
__device__ __forceinline__ void load_row6(const float* __restrict__ p, long base,
                                          bool rowv, bool ledge, bool redge,
                                          int lane, float v[6]) {
    float4 c;
    if (rowv) c = *(const float4*)(p + base);
    else      c = make_float4(0.f, 0.f, 0.f, 0.f);
    float lw = __shfl_up(c.w, 1);    // lane-1's col+3  -> my col-1
    float rx = __shfl_down(c.x, 1);  // lane+1's col    -> my col+4
    if (lane == 0)  lw = (ledge || !rowv) ? 0.0f : p[base - 1];
    if (lane == 63) rx = (redge || !rowv) ? 0.0f : p[base + 4];
    v[0] = lw; v[1] = c.x; v[2] = c.y; v[3] = c.z; v[4] = c.w; v[5] = rx;
}

__global__ __launch_bounds__(256) void WeightedAverage_kernel(
    const float* __restrict__ x,
    const int*   __restrict__ alpha_p,
    float*       __restrict__ out)
{
    int g    = blockIdx.x * 256 + threadIdx.x;  // one float4-group (4 px) per thread
    int lane = threadIdx.x & 63;
    int col  = (g & 127) << 2;                  // 128 groups per row
    int h    = (g >> 7) & 511;
    int n    = g >> 16;
    bool ledge = (col == 0);
    bool redge = (col + 4 == WW);

    // exp(-d^2/alpha) = exp2(d^2 * m), m = -log2(e)/alpha
    float m = -1.4426950408889634f / (float)(*alpha_p);

    const float* Lp = x + (size_t)n * 3 * HWSZ;
    const float* Ap = Lp + HWSZ;
    const float* Bp = Lp + 2 * HWSZ;

    // L neighborhood: 3 rows x 6 cols in registers
    float Lr[3][6];
    long rb[3];
    bool rv[3];
#pragma unroll
    for (int i = 0; i < 3; ++i) {
        int r = h - 1 + i;
        rv[i] = ((unsigned)r < (unsigned)HH);
        rb[i] = (long)r * WW + col;
        load_row6(Lp, rb[i], rv[i], ledge, redge, lane, Lr[i]);
    }

    float l[4] = { Lr[1][1], Lr[1][2], Lr[1][3], Lr[1][4] };
    float den[4] = {0.f,0.f,0.f,0.f};
    float na[4]  = {0.f,0.f,0.f,0.f};
    float nb[4]  = {0.f,0.f,0.f,0.f};

#pragma unroll
    for (int i = 0; i < 3; ++i) {
        float Ar[6], Br[6];
        load_row6(Ap, rb[i], rv[i], ledge, redge, lane, Ar);
        load_row6(Bp, rb[i], rv[i], ledge, redge, lane, Br);
#pragma unroll
        for (int dx = 0; dx < 3; ++dx) {
#pragma unroll
            for (int j = 0; j < 4; ++j) {
                float d  = Lr[i][j + dx] - l[j];
                float wt = (i == 1 && dx == 1) ? 1.0f : exp2f(d * d * m);
                den[j] += wt;
                na[j]  += wt * Ar[j + dx];
                nb[j]  += wt * Br[j + dx];
            }
        }
    }

    float4 oa, ob;
    float r0 = __builtin_amdgcn_rcpf(den[0]);
    float r1 = __builtin_amdgcn_rcpf(den[1]);
    float r2 = __builtin_amdgcn_rcpf(den[2]);
    float r3 = __builtin_amdgcn_rcpf(den[3]);
    oa = make_float4(na[0]*r0, na[1]*r1, na[2]*r2, na[3]*r3);
    ob = make_float4(nb[0]*r0, nb[1]*r1, nb[2]*r2, nb[3]*r3);

    float* op = out + (size_t)n * 2 * HWSZ + (size_t)h * WW + col;
    *(float4*)(op)        = oa;
    *(float4*)(op + HWSZ) = ob;
}

extern "C" void kernel_launch(void* const* d_in, const int* in_sizes, int n_in,
                              void* d_out, int out_size, void* d_ws, size_t ws_size,
                              hipStream_t stream) {
    const float* x     = (const float*)d_in[0];
    const int*   alpha = (const int*)d_in[2];
    float*       out   = (float*)d_out;

    int groups = NB * HWSZ / 4;          // 1,048,576 threads (4 px each)
    dim3 grid(groups / 256);             // 4096 blocks
    WeightedAverage_kernel<<<grid, 256, 0, stream>>>(x, alpha, out);
}

// Round 4
// 107.585 us; speedup vs baseline: 1.0537x; 1.0537x over previous
//
#include <hip/hip_runtime.h>

// x_lab [16,3,512,512] fp32, patch=3, alpha from d_in[2], out [16,2,512,512] fp32
#define NB   16
#define HH   512
#define WW   512
#define HWSZ (HH * WW)

typedef float vfloat4 __attribute__((ext_vector_type(4)));  // native vector for nontemporal builtin

// 6 consecutive floats (col-1 .. col+4) for one row of one channel.
// Aligned float4 for cols 0..3 plus two bounds-predicated scalar loads for
// the halo. rowv is wave-uniform (h constant within a wave); ledge/redge
// affect at most one lane per wave. OOB -> 0 (zero padding).
__device__ __forceinline__ void load_row6(const float* __restrict__ p, int base,
                                          bool rowv, bool ledge, bool redge,
                                          float v[6]) {
    vfloat4 c = (vfloat4){0.f, 0.f, 0.f, 0.f};
    float lw = 0.0f, rx = 0.0f;
    if (rowv) {
        c = *(const vfloat4*)(p + base);
        if (!ledge) lw = p[base - 1];
        if (!redge) rx = p[base + 4];
    }
    v[0] = lw; v[1] = c.x; v[2] = c.y; v[3] = c.z; v[4] = c.w; v[5] = rx;
}

__global__ __launch_bounds__(256) void WeightedAverage_kernel(
    const float* __restrict__ x,
    const int*   __restrict__ alpha_p,
    float*       __restrict__ out)
{
    int g   = blockIdx.x * 256 + threadIdx.x;   // one 4-px group per thread
    int col = (g & 127) << 2;                   // 128 groups per row
    int h   = (g >> 7) & 511;
    int n   = g >> 16;
    bool ledge = (col == 0);
    bool redge = (col + 4 == WW);

    // exp(-d^2/alpha) = exp2(d^2 * m), m = -log2(e)/alpha
    float m = -1.4426950408889634f / (float)(*alpha_p);

    const float* Lp = x + (size_t)n * 3 * HWSZ;
    const float* Ap = Lp + HWSZ;
    const float* Bp = Lp + 2 * HWSZ;

    float Lr[3][6];
    int  rb[3];
    bool rv[3];
#pragma unroll
    for (int i = 0; i < 3; ++i) {
        int r = h - 1 + i;
        rv[i] = ((unsigned)r < (unsigned)HH);
        rb[i] = r * WW + col;
        load_row6(Lp, rb[i], rv[i], ledge, redge, Lr[i]);
    }

    float l[4] = { Lr[1][1], Lr[1][2], Lr[1][3], Lr[1][4] };
    float den[4] = {0.f,0.f,0.f,0.f};
    float na[4]  = {0.f,0.f,0.f,0.f};
    float nb[4]  = {0.f,0.f,0.f,0.f};

#pragma unroll
    for (int i = 0; i < 3; ++i) {
        float Ar[6], Br[6];
        load_row6(Ap, rb[i], rv[i], ledge, redge, Ar);
        load_row6(Bp, rb[i], rv[i], ledge, redge, Br);
#pragma unroll
        for (int dx = 0; dx < 3; ++dx) {
#pragma unroll
            for (int j = 0; j < 4; ++j) {
                float d  = Lr[i][j + dx] - l[j];
                float wt = (i == 1 && dx == 1) ? 1.0f : exp2f(d * d * m);
                den[j] += wt;
                na[j]  += wt * Ar[j + dx];
                nb[j]  += wt * Br[j + dx];
            }
        }
    }

    float r0 = __builtin_amdgcn_rcpf(den[0]);
    float r1 = __builtin_amdgcn_rcpf(den[1]);
    float r2 = __builtin_amdgcn_rcpf(den[2]);
    float r3 = __builtin_amdgcn_rcpf(den[3]);
    vfloat4 oa = (vfloat4){na[0]*r0, na[1]*r1, na[2]*r2, na[3]*r3};
    vfloat4 ob = (vfloat4){nb[0]*r0, nb[1]*r1, nb[2]*r2, nb[3]*r3};

    float* op = out + (size_t)n * 2 * HWSZ + (size_t)h * WW + col;
    __builtin_nontemporal_store(oa, (vfloat4*)op);          // output is write-once;
    __builtin_nontemporal_store(ob, (vfloat4*)(op + HWSZ)); // keep L2 for input halo
}

extern "C" void kernel_launch(void* const* d_in, const int* in_sizes, int n_in,
                              void* d_out, int out_size, void* d_ws, size_t ws_size,
                              hipStream_t stream) {
    const float* x     = (const float*)d_in[0];
    const int*   alpha = (const int*)d_in[2];
    float*       out   = (float*)d_out;

    int groups = NB * HWSZ / 4;          // 1,048,576 threads (4 px each)
    dim3 grid(groups / 256);             // 4096 blocks
    WeightedAverage_kernel<<<grid, 256, 0, stream>>>(x, alpha, out);
}